// Round 1
// baseline (370.636 us; speedup 1.0000x reference)
//
#include <hip/hip_runtime.h>

#define K0 3072
#define BPB 16           // batch rows per block
#define NWAVE 8
#define BLOCK (NWAVE * 64)

struct KtreeArgs {
  const float* x;
  const float* ap1; const float* ap2; const float* am1; const float* am2; const float* g0;
  const float* w[11];
  const float* bs[11];
  const float* root_w; const float* root_b;
  float* out;
};

__device__ __forceinline__ double lrelu(double v) {
  return v >= 0.0 ? v : 0.01 * v;
}

__global__ __launch_bounds__(BLOCK) void ktree_synapse_kernel(KtreeArgs A) {
  const int tid = threadIdx.x;
  const int w = tid >> 6;       // wave 0..7, owns k in [w*384, (w+1)*384)
  const int l = tid & 63;       // lane
  const int kb = w * 384 + l * 6;   // lane's first k (6 consecutive k per lane)

  // ---- preload per-lane params into registers (constant across all b) ----
  float ap1v[2][6], ap2v[2][6], am1v[2][6], am2v[2][6], g0v[2][6];
  #pragma unroll
  for (int r = 0; r < 2; ++r) {
    const int o = r * K0 + kb;
    #pragma unroll
    for (int j = 0; j < 6; ++j) {
      ap1v[r][j] = A.ap1[o + j];
      ap2v[r][j] = A.ap2[o + j];
      am1v[r][j] = A.am1[o + j];
      am2v[r][j] = A.am2[o + j];
      g0v[r][j]  = A.g0[o + j];
    }
  }
  // level 0 (f=3): lane owns nodes n0, n0+1 of the K=1024 level
  float w0v[2][6], b0v[2][2];
  const int n0 = w * 128 + 2 * l;
  #pragma unroll
  for (int r = 0; r < 2; ++r) {
    const int o = (r * 1024 + n0) * 3;
    #pragma unroll
    for (int j = 0; j < 6; ++j) w0v[r][j] = A.w[0][o + j];
    b0v[r][0] = A.bs[0][r * 1024 + n0];
    b0v[r][1] = A.bs[0][r * 1024 + n0 + 1];
  }
  // level 1 (1024 -> 512): lane owns node n1 = w*64 + l
  float w1v[2][2], b1v[2];
  const int n1 = w * 64 + l;
  #pragma unroll
  for (int r = 0; r < 2; ++r) {
    w1v[r][0] = A.w[1][(r * 512 + n1) * 2 + 0];
    w1v[r][1] = A.w[1][(r * 512 + n1) * 2 + 1];
    b1v[r]    = A.bs[1][r * 512 + n1];
  }
  // levels 2..7 (shuffle levels): out node m = w*cnt + l, cnt = 64>>(lvl-1)
  float wlv[6][2][2], blv[6][2];
  #pragma unroll
  for (int lvl = 2; lvl <= 7; ++lvl) {
    const int cnt  = 64 >> (lvl - 1);
    const int kout = 1024 >> lvl;           // K[lvl+1]
    const int m = w * cnt + (l < cnt ? l : cnt - 1);   // clamp for inactive lanes
    #pragma unroll
    for (int r = 0; r < 2; ++r) {
      wlv[lvl - 2][r][0] = A.w[lvl][(r * kout + m) * 2 + 0];
      wlv[lvl - 2][r][1] = A.w[lvl][(r * kout + m) * 2 + 1];
      blv[lvl - 2][r]    = A.bs[lvl][r * kout + m];
    }
  }

  __shared__ double lds[BPB][2][NWAVE];

  const int bbase = blockIdx.x * BPB;
  for (int bi = 0; bi < BPB; ++bi) {
    const int b = bbase + bi;
    float xv[6];
    const float* xp = A.x + (size_t)b * K0 + kb;
    #pragma unroll
    for (int j = 0; j < 6; ++j) xv[j] = xp[j];

    #pragma unroll
    for (int r = 0; r < 2; ++r) {
      double acc0 = (double)b0v[r][0];
      double acc1 = (double)b0v[r][1];
      #pragma unroll
      for (int j = 0; j < 6; ++j) {
        const double xd = (double)xv[j];
        double tp = fma((double)ap1v[r][j], xd, (double)ap2v[r][j]);
        double tm = fma((double)am1v[r][j], xd, (double)am2v[r][j]);
        tp = fmin(fmax(tp, -60.0), 60.0);
        tm = fmin(fmax(tm, -60.0), 60.0);
        const double gp = exp(tp);
        const double gm = exp(tm);
        const double gz = (double)g0v[r][j];
        const double num = fma(50.0, gp, fma(-70.0, gm, -65.0 * gz));
        const double den = gp + gm + gz;
        const double s = num / den;
        if (j < 3) acc0 = fma((double)w0v[r][j], s, acc0);
        else       acc1 = fma((double)w0v[r][j], s, acc1);
      }
      acc0 = lrelu(acc0);
      acc1 = lrelu(acc1);
      // level 1 (in-lane)
      double v = lrelu(fma((double)w1v[r][0], acc0,
                       fma((double)w1v[r][1], acc1, (double)b1v[r])));
      // levels 2..7 (cross-lane pair reduction)
      #pragma unroll
      for (int lvl = 2; lvl <= 7; ++lvl) {
        const double a = __shfl(v, 2 * l,     64);
        const double c = __shfl(v, 2 * l + 1, 64);
        v = lrelu(fma((double)wlv[lvl - 2][r][0], a,
                  fma((double)wlv[lvl - 2][r][1], c, (double)blv[lvl - 2][r])));
      }
      if (l == 0) lds[bi][r][w] = v;   // wave's K=8 node (index w)
    }
  }
  __syncthreads();

  // finisher: levels 8..10 + root, one thread per batch row
  if (tid < BPB) {
    const int b = bbase + tid;
    double o = (double)A.root_b[0];
    #pragma unroll
    for (int r = 0; r < 2; ++r) {
      double v8[8];
      #pragma unroll
      for (int q = 0; q < 8; ++q) v8[q] = lds[tid][r][q];
      double v4[4];
      #pragma unroll
      for (int n = 0; n < 4; ++n)
        v4[n] = lrelu(fma((double)A.w[8][(r * 4 + n) * 2 + 0], v8[2 * n],
                      fma((double)A.w[8][(r * 4 + n) * 2 + 1], v8[2 * n + 1],
                          (double)A.bs[8][r * 4 + n])));
      double v2[2];
      #pragma unroll
      for (int n = 0; n < 2; ++n)
        v2[n] = lrelu(fma((double)A.w[9][(r * 2 + n) * 2 + 0], v4[2 * n],
                      fma((double)A.w[9][(r * 2 + n) * 2 + 1], v4[2 * n + 1],
                          (double)A.bs[9][r * 2 + n])));
      const double v1 = lrelu(fma((double)A.w[10][r * 2 + 0], v2[0],
                              fma((double)A.w[10][r * 2 + 1], v2[1],
                                  (double)A.bs[10][r])));
      o = fma((double)A.root_w[r], v1, o);
    }
    A.out[b] = (float)o;
  }
}

extern "C" void kernel_launch(void* const* d_in, const int* in_sizes, int n_in,
                              void* d_out, int out_size, void* d_ws, size_t ws_size,
                              hipStream_t stream) {
  KtreeArgs A;
  A.x   = (const float*)d_in[0];
  A.ap1 = (const float*)d_in[1];
  A.ap2 = (const float*)d_in[2];
  A.am1 = (const float*)d_in[3];
  A.am2 = (const float*)d_in[4];
  A.g0  = (const float*)d_in[5];
  for (int i = 0; i < 11; ++i) {
    A.w[i]  = (const float*)d_in[6 + 2 * i];
    A.bs[i] = (const float*)d_in[7 + 2 * i];
  }
  A.root_w = (const float*)d_in[28];
  A.root_b = (const float*)d_in[29];
  A.out = (float*)d_out;

  const int grid = 8192 / BPB;   // 512 blocks x 512 threads
  hipLaunchKernelGGL(ktree_synapse_kernel, dim3(grid), dim3(BLOCK), 0, stream, A);
}

// Round 2
// 216.448 us; speedup vs baseline: 1.7124x; 1.7124x over previous
//
#include <hip/hip_runtime.h>

#define K0 3072
#define BPB 32            // batch rows per block
#define BLOCK 1024        // 16 waves: wave = (r<<3) | chunk

struct KtreeArgs {
  const float* x;
  const float* ap1; const float* ap2; const float* am1; const float* am2; const float* g0;
  const float* w[11];
  const float* bs[11];
  const float* root_w; const float* root_b;
  float* out;
};

__device__ __forceinline__ float lrelu(float v) {
  return v >= 0.0f ? v : 0.01f * v;
}

__device__ __forceinline__ int bitrev(int v, int bits) {
  int r = 0;
  for (int i = 0; i < bits; ++i) r |= ((v >> i) & 1) << (bits - 1 - i);
  return r;
}

__global__ __launch_bounds__(BLOCK, 4) void ktree_synapse_kernel(KtreeArgs A) {
  const int tid = threadIdx.x;
  const int wv  = tid >> 6;        // 0..15
  const int l   = tid & 63;
  const int c   = wv & 7;          // k-chunk: K=8-level node index
  const int r   = wv >> 3;         // population 0/1

  // bit-reversed placement: lane l owns K=512-level node c*64 + rev6(l),
  // so levels 2..7 reduce with single shfl_down per level (stride 32..1).
  const int r6      = bitrev(l, 6);
  const int node512 = c * 64 + r6;
  const int kb      = node512 * 6;          // 6 consecutive k per lane

  // ---- preload per-lane params (registers, constant across rows) ----
  float p1[6], p2[6], m1[6], m2[6], z0[6];
  {
    const int o = r * K0 + kb;
    #pragma unroll
    for (int j = 0; j < 6; ++j) {
      p1[j] = A.ap1[o + j];
      p2[j] = A.ap2[o + j];
      m1[j] = A.am1[o + j];
      m2[j] = A.am2[o + j];
      z0[j] = A.g0[o + j];
    }
  }
  // level 0 (3072->1024, f=3): lane owns K=1024 nodes 2*node512, 2*node512+1
  float w0v[6], b0a, b0b;
  {
    const int o = (r * 1024 + 2 * node512) * 3;
    #pragma unroll
    for (int j = 0; j < 6; ++j) w0v[j] = A.w[0][o + j];
    b0a = A.bs[0][r * 1024 + 2 * node512];
    b0b = A.bs[0][r * 1024 + 2 * node512 + 1];
  }
  // level 1 (1024->512): lane owns node512
  float w1a, w1b, b1v;
  {
    const int n = r * 512 + node512;
    w1a = A.w[1][n * 2 + 0];
    w1b = A.w[1][n * 2 + 1];
    b1v = A.bs[1][n];
  }
  // levels 2..7 (512->8), butterfly steps s=0..5, stride 32>>s
  float ws0[6], ws1[6], bsv[6];
  #pragma unroll
  for (int s = 0; s < 6; ++s) {
    const int active = (l < (64 >> (s + 1)));
    const int local  = active ? bitrev(l, 5 - s) : 0;   // parent node within chunk
    const int ktot   = 256 >> s;                        // K[3+s] nodes per r
    const int m      = r * ktot + c * (32 >> s) + local;
    ws0[s] = A.w[2 + s][m * 2 + 0];
    ws1[s] = A.w[2 + s][m * 2 + 1];
    bsv[s] = A.bs[2 + s][m];
  }

  __shared__ float lds_buf[BPB][2][8];

  const int bbase = blockIdx.x * BPB;
  const float LOG2E = 1.4426950408889634f;

  for (int bi = 0; bi < BPB; ++bi) {
    const int b = bbase + bi;
    const float2* xp = reinterpret_cast<const float2*>(A.x + (size_t)b * K0 + kb);
    const float2 xa = xp[0], xb = xp[1], xc = xp[2];
    const float xv[6] = {xa.x, xa.y, xb.x, xb.y, xc.x, xc.y};

    float acc0 = b0a, acc1 = b0b;
    #pragma unroll
    for (int j = 0; j < 6; ++j) {
      float tp = fmaf(p1[j], xv[j], p2[j]);
      float tm = fmaf(m1[j], xv[j], m2[j]);
      tp = fminf(fmaxf(tp, -60.0f), 60.0f);
      tm = fminf(fmaxf(tm, -60.0f), 60.0f);
      const float gp = __expf(tp);
      const float gm = __expf(tm);
      const float gz = z0[j];
      const float num = fmaf(50.0f, gp, fmaf(-70.0f, gm, -65.0f * gz));
      const float den = gp + gm + gz;
      float rr = __builtin_amdgcn_rcpf(den);
      rr = rr * fmaf(-den, rr, 2.0f);          // Newton: ~0.5 ulp
      const float s = num * rr;
      if (j < 3) acc0 = fmaf(w0v[j], s, acc0);
      else       acc1 = fmaf(w0v[j], s, acc1);
    }
    acc0 = lrelu(acc0);
    acc1 = lrelu(acc1);
    float v = lrelu(fmaf(w1a, acc0, fmaf(w1b, acc1, b1v)));

    #pragma unroll
    for (int s = 0; s < 6; ++s) {
      const float u = __shfl_down(v, 32 >> s, 64);
      v = lrelu(fmaf(ws0[s], v, fmaf(ws1[s], u, bsv[s])));
    }
    if (l == 0) lds_buf[bi][r][c] = v;
  }
  __syncthreads();

  // finisher: levels 8..10 + root, one thread per batch row (fp32)
  if (tid < BPB) {
    const int b = bbase + tid;
    float o = A.root_b[0];
    #pragma unroll
    for (int rr = 0; rr < 2; ++rr) {
      float v8[8];
      #pragma unroll
      for (int q = 0; q < 8; ++q) v8[q] = lds_buf[tid][rr][q];
      float v4[4];
      #pragma unroll
      for (int n = 0; n < 4; ++n)
        v4[n] = lrelu(fmaf(A.w[8][(rr * 4 + n) * 2 + 0], v8[2 * n],
                      fmaf(A.w[8][(rr * 4 + n) * 2 + 1], v8[2 * n + 1],
                           A.bs[8][rr * 4 + n])));
      float v2[2];
      #pragma unroll
      for (int n = 0; n < 2; ++n)
        v2[n] = lrelu(fmaf(A.w[9][(rr * 2 + n) * 2 + 0], v4[2 * n],
                      fmaf(A.w[9][(rr * 2 + n) * 2 + 1], v4[2 * n + 1],
                           A.bs[9][rr * 2 + n])));
      const float v1 = lrelu(fmaf(A.w[10][rr * 2 + 0], v2[0],
                             fmaf(A.w[10][rr * 2 + 1], v2[1],
                                  A.bs[10][rr])));
      o = fmaf(A.root_w[rr], v1, o);
    }
    A.out[b] = o;
  }
}

extern "C" void kernel_launch(void* const* d_in, const int* in_sizes, int n_in,
                              void* d_out, int out_size, void* d_ws, size_t ws_size,
                              hipStream_t stream) {
  KtreeArgs A;
  A.x   = (const float*)d_in[0];
  A.ap1 = (const float*)d_in[1];
  A.ap2 = (const float*)d_in[2];
  A.am1 = (const float*)d_in[3];
  A.am2 = (const float*)d_in[4];
  A.g0  = (const float*)d_in[5];
  for (int i = 0; i < 11; ++i) {
    A.w[i]  = (const float*)d_in[6 + 2 * i];
    A.bs[i] = (const float*)d_in[7 + 2 * i];
  }
  A.root_w = (const float*)d_in[28];
  A.root_b = (const float*)d_in[29];
  A.out = (float*)d_out;

  const int grid = 8192 / BPB;   // 256 blocks x 1024 threads
  hipLaunchKernelGGL(ktree_synapse_kernel, dim3(grid), dim3(BLOCK), 0, stream, A);
}